// Round 1
// baseline (435.792 us; speedup 1.0000x reference)
//
#include <hip/hip_runtime.h>
#include <math.h>

// SSIM loss, fused single-pass. fp32 [32,1,1024,1024] x2 -> scalar.
// Separable 11x11 Gaussian of 5 fields {a,b,a2,b2,ab}.
// Round-6: register-allocator fix. r5 still showed VGPR_Count=60 with ~120+
// live floats -> allocator split the frame ~60 arch + ~64 acc VGPRs chasing a
// 4-waves/EU occupancy target; every ring fma became
// accvgpr_read+fma+accvgpr_write (~326 VALU instr/step measured vs ~175 in
// source). Fix: drop __launch_bounds__(256,2) and instead declare
//   amdgpu_flat_work_group_size(256,256) + amdgpu_waves_per_eu(1,2)
// -> 512-reg budget, occupancy target <=2 waves/EU, no AGPR split motive.
// Everything else byte-identical to r5:
//  - weights used DIRECTLY from the kernarg struct (SGPRs; v_fma_f32 takes
//    one SGPR operand).
//  - all-scalar math; LDS stays (img1,img2)-interleaved float2 for b64 reads.
//  - staging loads use clamped addresses + value select (no branches around
//    loads inside the pipelined region).
//  - 1 row per barrier phase, loads issued 2 phases ahead of their LDS commit.
// Tile 256 cols x 128 rows; grid 4x8x32 = 1024 blocks = 4/CU in one round.

typedef float v2f __attribute__((ext_vector_type(2)));

#define IMG_W 1024
#define IMG_H 1024
#define NIMG  32
#define TW    256
#define TH    128
#define HALO  5
#define KW    11
#define ROWS  (TH + 2*HALO)   // 138 staged rows
#define NSO   13              // 13*11 = 143 unrolled steps, tail guarded off
#define SBP   268             // LDS row stride in v2f (266 used, 16B-pad)

#define C1f (0.01f * 0.01f)
#define C2f (0.03f * 0.03f)

struct GW { float w[KW]; };

__global__ __attribute__((amdgpu_flat_work_group_size(256, 256)))
__attribute__((amdgpu_waves_per_eu(1, 2)))
void ssim_main(const float* __restrict__ img1, const float* __restrict__ img2,
               double* __restrict__ acc_out, GW gw)
{
    alignas(16) __shared__ v2f sb[2][SBP];
    __shared__ float wsum[4];

    const int tid = threadIdx.x;
    const int c0 = blockIdx.x * TW;
    const int r0 = blockIdx.y * TH;
    const size_t imgoff = (size_t)blockIdx.z * (size_t)(IMG_W * IMG_H);
    const float* p1 = img1 + imgoff;
    const float* p2 = img2 + imgoff;

    // column geometry (uniform over rows); addresses clamped, OOB zeroed by select
    const int  gc_m   = c0 - HALO + tid;
    const int  gcc_m  = min(max(gc_m, 0), IMG_W - 1);
    const bool cok_m  = ((unsigned)gc_m < (unsigned)IMG_W);
    const int  gc_h   = c0 - HALO + TW + tid;            // used by tid<10
    const int  gcc_h  = min(max(gc_h, 0), IMG_W - 1);
    const bool cok_h  = (tid < 2 * HALO) && ((unsigned)gc_h < (unsigned)IMG_W);

    // vertical ring: 5 fields x 11 slots = 55 floats (must stay in arch VGPRs)
    float r_m1[KW], r_m2[KW], r_sa[KW], r_sb[KW], r_ab[KW];
#pragma unroll
    for (int j = 0; j < KW; ++j) {
        r_m1[j] = 0.f; r_m2[j] = 0.f; r_sa[j] = 0.f; r_sb[j] = 0.f; r_ab[j] = 0.f;
    }

    float lsum = 0.0f;

    // staging registers for one row: [a_main, b_main, a_halo, b_halo]
    float s0, s1, s2, s3;

    auto issue = [&](int s) {           // global -> regs for staged row s
        const int gr  = r0 + s - HALO;
        const bool rok = ((unsigned)gr < (unsigned)IMG_H);
        const size_t rbase = (size_t)min(max(gr, 0), IMG_H - 1) * IMG_W;
        float a0 = p1[rbase + gcc_m];
        float b0 = p2[rbase + gcc_m];
        float a1 = p1[rbase + gcc_h];
        float b1 = p2[rbase + gcc_h];
        const bool okm = rok && cok_m;
        const bool okh = rok && cok_h;
        s0 = okm ? a0 : 0.f;
        s1 = okm ? b0 : 0.f;
        s2 = okh ? a1 : 0.f;
        s3 = okh ? b1 : 0.f;
    };
    auto commit = [&](int s) {          // regs -> LDS buffer s&1
        v2f* dst = sb[s & 1];
        v2f t; t.x = s0; t.y = s1;
        dst[tid] = t;
        if (tid < 2 * HALO) { v2f t2; t2.x = s2; t2.y = s3; dst[TW + tid] = t2; }
    };

    issue(0); commit(0);    // row 0 straight to LDS
    issue(1);               // row 1 in flight in regs

    for (int so = 0; so < NSO; ++so) {
#pragma unroll
        for (int u = 0; u < KW; ++u) {
            const int s = so * KW + u;
            if (s < ROWS) {                 // uniform guard (tail steps dead)
                __syncthreads();            // phase s-1 reads done; buf (s+1)&1 free
                if (s + 1 < ROWS) commit(s + 1);
                if (s + 2 < ROWS) issue(s + 2);

                // horizontal 11-tap conv of the 5 fields (weights = SGPRs)
                const v2f* b = sb[s & 1];
                float hm1 = 0.f, hm2 = 0.f, hsa = 0.f, hsb = 0.f, hab = 0.f;
#pragma unroll
                for (int i = 0; i < KW; ++i) {
                    v2f E = b[tid + i];
                    const float a  = E.x;
                    const float bb = E.y;
                    const float wi = gw.w[i];
                    hm1 = __builtin_fmaf(wi, a, hm1);
                    hm2 = __builtin_fmaf(wi, bb, hm2);
                    hsa = __builtin_fmaf(wi, a * a, hsa);
                    hsb = __builtin_fmaf(wi, bb * bb, hsb);
                    hab = __builtin_fmaf(wi, a * bb, hab);
                }

                // vertical ring accumulate; slot j fresh-starts when k==0
#pragma unroll
                for (int j = 0; j < KW; ++j) {
                    const int k = (u - j + KW) % KW;   // compile-time after unroll
                    const float wk = gw.w[k];
                    if (k == 0) {
                        r_m1[j] = wk * hm1; r_m2[j] = wk * hm2;
                        r_sa[j] = wk * hsa; r_sb[j] = wk * hsb;
                        r_ab[j] = wk * hab;
                    } else {
                        r_m1[j] = __builtin_fmaf(wk, hm1, r_m1[j]);
                        r_m2[j] = __builtin_fmaf(wk, hm2, r_m2[j]);
                        r_sa[j] = __builtin_fmaf(wk, hsa, r_sa[j]);
                        r_sb[j] = __builtin_fmaf(wk, hsb, r_sb[j]);
                        r_ab[j] = __builtin_fmaf(wk, hab, r_ab[j]);
                    }
                }

                // output row r = s-10 completes in slot (u+1)%11
                if (s >= 10) {
                    const int je = (u + 1) % KW;
                    const float mu1 = r_m1[je], mu2 = r_m2[je];
                    const float caa = r_sa[je], cbb = r_sb[je], cab = r_ab[je];
                    const float mu1s = mu1 * mu1, mu2s = mu2 * mu2, mu12 = mu1 * mu2;
                    const float sg1 = caa - mu1s, sg2 = cbb - mu2s, sg12 = cab - mu12;
                    const float num = (2.0f * mu12 + C1f) * (2.0f * sg12 + C2f);
                    const float den = (mu1s + mu2s + C1f) * (sg1 + sg2 + C2f);
                    lsum = __builtin_fmaf(num, __builtin_amdgcn_rcpf(den), lsum);
                }
            }
        }
    }

    // block reduction: wave shuffle then LDS across the 4 waves
    float v = lsum;
#pragma unroll
    for (int off = 32; off > 0; off >>= 1) v += __shfl_down(v, off);
    __syncthreads();
    if ((tid & 63) == 0) wsum[tid >> 6] = v;
    __syncthreads();
    if (tid == 0) {
        float bsum = wsum[0] + wsum[1] + wsum[2] + wsum[3];
        atomicAdd(acc_out, (double)bsum);
    }
}

__global__ void ssim_finalize(const double* __restrict__ acc, float* __restrict__ out)
{
    out[0] = 1.0f - (float)(acc[0] * (1.0 / ((double)NIMG * IMG_W * IMG_H)));
}

extern "C" void kernel_launch(void* const* d_in, const int* in_sizes, int n_in,
                              void* d_out, int out_size, void* d_ws, size_t ws_size,
                              hipStream_t stream)
{
    const float* img1 = (const float*)d_in[0];
    const float* img2 = (const float*)d_in[1];
    float* out = (float*)d_out;
    double* accbuf = (double*)d_ws;

    // Gaussian weights exactly as the reference: exp in f64, cast f32, normalize
    GW gw;
    {
        float g[KW];
        double s = 0.0;
        for (int i = 0; i < KW; ++i) {
            int x = i - KW / 2;
            g[i] = (float)exp(-(double)(x * x) / (2.0 * 1.5 * 1.5));
            s += (double)g[i];
        }
        for (int i = 0; i < KW; ++i) gw.w[i] = (float)((double)g[i] / s);
    }

    hipMemsetAsync(accbuf, 0, sizeof(double), stream);
    dim3 grid(IMG_W / TW, IMG_H / TH, NIMG);
    ssim_main<<<grid, 256, 0, stream>>>(img1, img2, accbuf, gw);
    ssim_finalize<<<1, 1, 0, stream>>>(accbuf, out);
}

// Round 2
// 362.809 us; speedup vs baseline: 1.2012x; 1.2012x over previous
//
#include <hip/hip_runtime.h>
#include <math.h>

// SSIM loss, fused single-pass. fp32 [32,1,1024,1024] x2 -> scalar.
// Separable 11x11 Gaussian of 5 fields {a,b,a2,b2,ab}.
// Round-7: occupancy fix. Post-mortem of r5/r6: VALU-busy TIME is invariant
// (~148us) across a 60->88 VGPR change => no AGPR-copy inflation; real VALU
// issue time is ~75us (VALUBusy formula overcounts 2x on gfx950 via gfx94x
// 4cyc/wave64 assumption). r6 dropped occupancy 36.6%->22% and dur rose
// 202->265us with an identical instruction stream => kernel is LATENCY-bound.
// r5 was grid-capped at 4 blocks/CU (1024 blocks, 16 waves/CU). Fix: halve
// tile height TH 128->64 -> 2048 blocks = 8 blocks/CU -> up to 32 waves/CU.
// Cost: halo overhead 74/64 vs 138/128 staged rows (+7% fetch). Everything
// else identical to r5 (launch_bounds(256,2), weights in SGPRs via kernarg,
// float2-interleaved LDS, clamped-address staging, 1 row/barrier phase,
// loads 2 phases ahead).
// Tile 256 cols x 64 rows; grid 4x16x32 = 2048 blocks = 8/CU.

typedef float v2f __attribute__((ext_vector_type(2)));

#define IMG_W 1024
#define IMG_H 1024
#define NIMG  32
#define TW    256
#define TH    64
#define HALO  5
#define KW    11
#define ROWS  (TH + 2*HALO)   // 74 staged rows
#define NSO   7               // 7*11 = 77 unrolled steps, tail guarded off
#define SBP   268             // LDS row stride in v2f (266 used, 16B-pad)

#define C1f (0.01f * 0.01f)
#define C2f (0.03f * 0.03f)

struct GW { float w[KW]; };

__global__ __launch_bounds__(256, 2)
void ssim_main(const float* __restrict__ img1, const float* __restrict__ img2,
               double* __restrict__ acc_out, GW gw)
{
    alignas(16) __shared__ v2f sb[2][SBP];
    __shared__ float wsum[4];

    const int tid = threadIdx.x;
    const int c0 = blockIdx.x * TW;
    const int r0 = blockIdx.y * TH;
    const size_t imgoff = (size_t)blockIdx.z * (size_t)(IMG_W * IMG_H);
    const float* p1 = img1 + imgoff;
    const float* p2 = img2 + imgoff;

    // column geometry (uniform over rows); addresses clamped, OOB zeroed by select
    const int  gc_m   = c0 - HALO + tid;
    const int  gcc_m  = min(max(gc_m, 0), IMG_W - 1);
    const bool cok_m  = ((unsigned)gc_m < (unsigned)IMG_W);
    const int  gc_h   = c0 - HALO + TW + tid;            // used by tid<10
    const int  gcc_h  = min(max(gc_h, 0), IMG_W - 1);
    const bool cok_h  = (tid < 2 * HALO) && ((unsigned)gc_h < (unsigned)IMG_W);

    // vertical ring: 5 fields x 11 slots = 55 floats
    float r_m1[KW], r_m2[KW], r_sa[KW], r_sb[KW], r_ab[KW];
#pragma unroll
    for (int j = 0; j < KW; ++j) {
        r_m1[j] = 0.f; r_m2[j] = 0.f; r_sa[j] = 0.f; r_sb[j] = 0.f; r_ab[j] = 0.f;
    }

    float lsum = 0.0f;

    // staging registers for one row: [a_main, b_main, a_halo, b_halo]
    float s0, s1, s2, s3;

    auto issue = [&](int s) {           // global -> regs for staged row s
        const int gr  = r0 + s - HALO;
        const bool rok = ((unsigned)gr < (unsigned)IMG_H);
        const size_t rbase = (size_t)min(max(gr, 0), IMG_H - 1) * IMG_W;
        float a0 = p1[rbase + gcc_m];
        float b0 = p2[rbase + gcc_m];
        float a1 = p1[rbase + gcc_h];
        float b1 = p2[rbase + gcc_h];
        const bool okm = rok && cok_m;
        const bool okh = rok && cok_h;
        s0 = okm ? a0 : 0.f;
        s1 = okm ? b0 : 0.f;
        s2 = okh ? a1 : 0.f;
        s3 = okh ? b1 : 0.f;
    };
    auto commit = [&](int s) {          // regs -> LDS buffer s&1
        v2f* dst = sb[s & 1];
        v2f t; t.x = s0; t.y = s1;
        dst[tid] = t;
        if (tid < 2 * HALO) { v2f t2; t2.x = s2; t2.y = s3; dst[TW + tid] = t2; }
    };

    issue(0); commit(0);    // row 0 straight to LDS
    issue(1);               // row 1 in flight in regs

    for (int so = 0; so < NSO; ++so) {
#pragma unroll
        for (int u = 0; u < KW; ++u) {
            const int s = so * KW + u;
            if (s < ROWS) {                 // uniform guard (tail steps dead)
                __syncthreads();            // phase s-1 reads done; buf (s+1)&1 free
                if (s + 1 < ROWS) commit(s + 1);
                if (s + 2 < ROWS) issue(s + 2);

                // horizontal 11-tap conv of the 5 fields (weights = SGPRs)
                const v2f* b = sb[s & 1];
                float hm1 = 0.f, hm2 = 0.f, hsa = 0.f, hsb = 0.f, hab = 0.f;
#pragma unroll
                for (int i = 0; i < KW; ++i) {
                    v2f E = b[tid + i];
                    const float a  = E.x;
                    const float bb = E.y;
                    const float wi = gw.w[i];
                    hm1 = __builtin_fmaf(wi, a, hm1);
                    hm2 = __builtin_fmaf(wi, bb, hm2);
                    hsa = __builtin_fmaf(wi, a * a, hsa);
                    hsb = __builtin_fmaf(wi, bb * bb, hsb);
                    hab = __builtin_fmaf(wi, a * bb, hab);
                }

                // vertical ring accumulate; slot j fresh-starts when k==0
#pragma unroll
                for (int j = 0; j < KW; ++j) {
                    const int k = (u - j + KW) % KW;   // compile-time after unroll
                    const float wk = gw.w[k];
                    if (k == 0) {
                        r_m1[j] = wk * hm1; r_m2[j] = wk * hm2;
                        r_sa[j] = wk * hsa; r_sb[j] = wk * hsb;
                        r_ab[j] = wk * hab;
                    } else {
                        r_m1[j] = __builtin_fmaf(wk, hm1, r_m1[j]);
                        r_m2[j] = __builtin_fmaf(wk, hm2, r_m2[j]);
                        r_sa[j] = __builtin_fmaf(wk, hsa, r_sa[j]);
                        r_sb[j] = __builtin_fmaf(wk, hsb, r_sb[j]);
                        r_ab[j] = __builtin_fmaf(wk, hab, r_ab[j]);
                    }
                }

                // output row r = s-10 completes in slot (u+1)%11
                if (s >= 10) {
                    const int je = (u + 1) % KW;
                    const float mu1 = r_m1[je], mu2 = r_m2[je];
                    const float caa = r_sa[je], cbb = r_sb[je], cab = r_ab[je];
                    const float mu1s = mu1 * mu1, mu2s = mu2 * mu2, mu12 = mu1 * mu2;
                    const float sg1 = caa - mu1s, sg2 = cbb - mu2s, sg12 = cab - mu12;
                    const float num = (2.0f * mu12 + C1f) * (2.0f * sg12 + C2f);
                    const float den = (mu1s + mu2s + C1f) * (sg1 + sg2 + C2f);
                    lsum = __builtin_fmaf(num, __builtin_amdgcn_rcpf(den), lsum);
                }
            }
        }
    }

    // block reduction: wave shuffle then LDS across the 4 waves
    float v = lsum;
#pragma unroll
    for (int off = 32; off > 0; off >>= 1) v += __shfl_down(v, off);
    __syncthreads();
    if ((tid & 63) == 0) wsum[tid >> 6] = v;
    __syncthreads();
    if (tid == 0) {
        float bsum = wsum[0] + wsum[1] + wsum[2] + wsum[3];
        atomicAdd(acc_out, (double)bsum);
    }
}

__global__ void ssim_finalize(const double* __restrict__ acc, float* __restrict__ out)
{
    out[0] = 1.0f - (float)(acc[0] * (1.0 / ((double)NIMG * IMG_W * IMG_H)));
}

extern "C" void kernel_launch(void* const* d_in, const int* in_sizes, int n_in,
                              void* d_out, int out_size, void* d_ws, size_t ws_size,
                              hipStream_t stream)
{
    const float* img1 = (const float*)d_in[0];
    const float* img2 = (const float*)d_in[1];
    float* out = (float*)d_out;
    double* accbuf = (double*)d_ws;

    // Gaussian weights exactly as the reference: exp in f64, cast f32, normalize
    GW gw;
    {
        float g[KW];
        double s = 0.0;
        for (int i = 0; i < KW; ++i) {
            int x = i - KW / 2;
            g[i] = (float)exp(-(double)(x * x) / (2.0 * 1.5 * 1.5));
            s += (double)g[i];
        }
        for (int i = 0; i < KW; ++i) gw.w[i] = (float)((double)g[i] / s);
    }

    hipMemsetAsync(accbuf, 0, sizeof(double), stream);
    dim3 grid(IMG_W / TW, IMG_H / TH, NIMG);
    ssim_main<<<grid, 256, 0, stream>>>(img1, img2, accbuf, gw);
    ssim_finalize<<<1, 1, 0, stream>>>(accbuf, out);
}

// Round 3
// 343.681 us; speedup vs baseline: 1.2680x; 1.0557x over previous
//
#include <hip/hip_runtime.h>
#include <math.h>

// SSIM loss, fused single-pass. fp32 [32,1,1024,1024] x2 -> scalar.
// Separable 11x11 Gaussian of 5 fields {a,b,a2,b2,ab}.
// Round-8: packed-fp32 math. r7 post-mortem: doubling blocks/CU (4->8) left
// occupancy AND dur unchanged (~12 waves/CU resident, 202us) while absorbing
// +7% extra halo work => issue-throughput-bound, occupancy lever exhausted.
// Fix: cut issued instructions with VOP3P packed fp32 (v_pk_fma_f32 /
// v_pk_mul_f32, CDNA2+). Fields pair as float2 lanes: (m1,m2), (sa,sb), ab
// scalar. LDS already stores (a,b) interleaved => horizontal tap = pk_fma +
// pk_mul + pk_fma + mul + fma = 5 instrs (was 8); ring slot = 2 pk_fma + fma
// = 3 (was 5). Per-row math 143 -> 88 VALU. Weights passed PRE-PAIRED in the
// kernarg (v2f wp[11]) so pk-ops take them as SGPR pairs -- no VGPR splats.
// Ring stays 55 floats (now aligned pairs) -> VGPR ~60, occupancy regime
// unchanged. Everything else identical to r7.
// Tile 256 cols x 64 rows; grid 4x16x32 = 2048 blocks = 8/CU.

typedef float v2f __attribute__((ext_vector_type(2)));

#define IMG_W 1024
#define IMG_H 1024
#define NIMG  32
#define TW    256
#define TH    64
#define HALO  5
#define KW    11
#define ROWS  (TH + 2*HALO)   // 74 staged rows
#define NSO   7               // 7*11 = 77 unrolled steps, tail guarded off
#define SBP   268             // LDS row stride in v2f (266 used, 16B-pad)

#define C1f (0.01f * 0.01f)
#define C2f (0.03f * 0.03f)

struct GW { v2f wp[KW]; };    // wp[i] = (w[i], w[i]) -- pre-paired for VOP3P

__global__ __launch_bounds__(256, 2)
void ssim_main(const float* __restrict__ img1, const float* __restrict__ img2,
               double* __restrict__ acc_out, GW gw)
{
    alignas(16) __shared__ v2f sb[2][SBP];
    __shared__ float wsum[4];

    const int tid = threadIdx.x;
    const int c0 = blockIdx.x * TW;
    const int r0 = blockIdx.y * TH;
    const size_t imgoff = (size_t)blockIdx.z * (size_t)(IMG_W * IMG_H);
    const float* p1 = img1 + imgoff;
    const float* p2 = img2 + imgoff;

    // column geometry (uniform over rows); addresses clamped, OOB zeroed by select
    const int  gc_m   = c0 - HALO + tid;
    const int  gcc_m  = min(max(gc_m, 0), IMG_W - 1);
    const bool cok_m  = ((unsigned)gc_m < (unsigned)IMG_W);
    const int  gc_h   = c0 - HALO + TW + tid;            // used by tid<10
    const int  gcc_h  = min(max(gc_h, 0), IMG_W - 1);
    const bool cok_h  = (tid < 2 * HALO) && ((unsigned)gc_h < (unsigned)IMG_W);

    // vertical ring: (m1,m2) pairs, (sa,sb) pairs, ab scalar = 55 floats
    v2f  r_m[KW], r_s[KW];
    float r_ab[KW];
#pragma unroll
    for (int j = 0; j < KW; ++j) {
        r_m[j] = (v2f)0.f; r_s[j] = (v2f)0.f; r_ab[j] = 0.f;
    }

    float lsum = 0.0f;

    // staging registers for one row: [a_main, b_main, a_halo, b_halo]
    float s0, s1, s2, s3;

    auto issue = [&](int s) {           // global -> regs for staged row s
        const int gr  = r0 + s - HALO;
        const bool rok = ((unsigned)gr < (unsigned)IMG_H);
        const size_t rbase = (size_t)min(max(gr, 0), IMG_H - 1) * IMG_W;
        float a0 = p1[rbase + gcc_m];
        float b0 = p2[rbase + gcc_m];
        float a1 = p1[rbase + gcc_h];
        float b1 = p2[rbase + gcc_h];
        const bool okm = rok && cok_m;
        const bool okh = rok && cok_h;
        s0 = okm ? a0 : 0.f;
        s1 = okm ? b0 : 0.f;
        s2 = okh ? a1 : 0.f;
        s3 = okh ? b1 : 0.f;
    };
    auto commit = [&](int s) {          // regs -> LDS buffer s&1
        v2f* dst = sb[s & 1];
        v2f t; t.x = s0; t.y = s1;
        dst[tid] = t;
        if (tid < 2 * HALO) { v2f t2; t2.x = s2; t2.y = s3; dst[TW + tid] = t2; }
    };

    issue(0); commit(0);    // row 0 straight to LDS
    issue(1);               // row 1 in flight in regs

    for (int so = 0; so < NSO; ++so) {
#pragma unroll
        for (int u = 0; u < KW; ++u) {
            const int s = so * KW + u;
            if (s < ROWS) {                 // uniform guard (tail steps dead)
                __syncthreads();            // phase s-1 reads done; buf (s+1)&1 free
                if (s + 1 < ROWS) commit(s + 1);
                if (s + 2 < ROWS) issue(s + 2);

                // horizontal 11-tap conv, packed: hm=(m1,m2) hs=(sa,sb) hab scalar
                const v2f* b = sb[s & 1];
                v2f hm = (v2f)0.f, hs = (v2f)0.f;
                float hab = 0.f;
#pragma unroll
                for (int i = 0; i < KW; ++i) {
                    const v2f E  = b[tid + i];        // (a, b) packed
                    const v2f wv = gw.wp[i];          // (w, w) SGPR pair
                    hm = __builtin_elementwise_fma(wv, E, hm);        // pk_fma
                    const v2f P = E * E;                              // pk_mul
                    hs = __builtin_elementwise_fma(wv, P, hs);        // pk_fma
                    hab = __builtin_fmaf(wv.x, E.x * E.y, hab);       // mul+fma
                }

                // vertical ring accumulate; slot j fresh-starts when k==0
#pragma unroll
                for (int j = 0; j < KW; ++j) {
                    const int k = (u - j + KW) % KW;   // compile-time after unroll
                    const v2f  wv = gw.wp[k];
                    const float wk = wv.x;
                    if (k == 0) {
                        r_m[j] = wv * hm;                              // pk_mul
                        r_s[j] = wv * hs;                              // pk_mul
                        r_ab[j] = wk * hab;
                    } else {
                        r_m[j] = __builtin_elementwise_fma(wv, hm, r_m[j]);
                        r_s[j] = __builtin_elementwise_fma(wv, hs, r_s[j]);
                        r_ab[j] = __builtin_fmaf(wk, hab, r_ab[j]);
                    }
                }

                // output row r = s-10 completes in slot (u+1)%11
                if (s >= 10) {
                    const int je = (u + 1) % KW;
                    const v2f  mu  = r_m[je];          // (mu1, mu2)
                    const v2f  cs  = r_s[je];          // (caa, cbb)
                    const float cab = r_ab[je];
                    const v2f  mus = mu * mu;          // (mu1^2, mu2^2)
                    const float mu12 = mu.x * mu.y;
                    const v2f  sg  = cs - mus;         // (sg1, sg2)
                    const float sg12 = cab - mu12;
                    const float num = (2.0f * mu12 + C1f) * (2.0f * sg12 + C2f);
                    const float den = (mus.x + mus.y + C1f) * (sg.x + sg.y + C2f);
                    lsum = __builtin_fmaf(num, __builtin_amdgcn_rcpf(den), lsum);
                }
            }
        }
    }

    // block reduction: wave shuffle then LDS across the 4 waves
    float v = lsum;
#pragma unroll
    for (int off = 32; off > 0; off >>= 1) v += __shfl_down(v, off);
    __syncthreads();
    if ((tid & 63) == 0) wsum[tid >> 6] = v;
    __syncthreads();
    if (tid == 0) {
        float bsum = wsum[0] + wsum[1] + wsum[2] + wsum[3];
        atomicAdd(acc_out, (double)bsum);
    }
}

__global__ void ssim_finalize(const double* __restrict__ acc, float* __restrict__ out)
{
    out[0] = 1.0f - (float)(acc[0] * (1.0 / ((double)NIMG * IMG_W * IMG_H)));
}

extern "C" void kernel_launch(void* const* d_in, const int* in_sizes, int n_in,
                              void* d_out, int out_size, void* d_ws, size_t ws_size,
                              hipStream_t stream)
{
    const float* img1 = (const float*)d_in[0];
    const float* img2 = (const float*)d_in[1];
    float* out = (float*)d_out;
    double* accbuf = (double*)d_ws;

    // Gaussian weights exactly as the reference: exp in f64, cast f32, normalize
    GW gw;
    {
        float g[KW];
        double s = 0.0;
        for (int i = 0; i < KW; ++i) {
            int x = i - KW / 2;
            g[i] = (float)exp(-(double)(x * x) / (2.0 * 1.5 * 1.5));
            s += (double)g[i];
        }
        for (int i = 0; i < KW; ++i) {
            float w = (float)((double)g[i] / s);
            gw.wp[i].x = w;
            gw.wp[i].y = w;
        }
    }

    hipMemsetAsync(accbuf, 0, sizeof(double), stream);
    dim3 grid(IMG_W / TW, IMG_H / TH, NIMG);
    ssim_main<<<grid, 256, 0, stream>>>(img1, img2, accbuf, gw);
    ssim_finalize<<<1, 1, 0, stream>>>(accbuf, out);
}